// Round 7
// baseline (841.010 us; speedup 1.0000x reference)
//
#include <hip/hip_runtime.h>
#include <hip/hip_bf16.h>
#include <cstdint>
#include <cstddef>

typedef __bf16 bf16_t;
typedef bf16_t bf16x8 __attribute__((ext_vector_type(8)));
typedef float  f32x4  __attribute__((ext_vector_type(4)));

__device__ __forceinline__ void gl_lds16(const void* g, void* l) {
  __builtin_amdgcn_global_load_lds(
      (const __attribute__((address_space(1))) void*)g,
      (__attribute__((address_space(3))) void*)l, 16, 0, 0);
}

#define BAR()  __builtin_amdgcn_s_barrier()
#define LGK0() asm volatile("s_waitcnt lgkmcnt(0)" ::: "memory")

// ---------------------------------------------------------------------------
// prep kernel: pack_x0 + 6 weight transposes + zero the flag region
// ---------------------------------------------------------------------------
__device__ __forceinline__ void transpose_tile(
    const float* __restrict__ W, bf16_t* __restrict__ Wt,
    int K, int N, int Kpad, int Npad, int bx, int by, int t)
{
  __shared__ float tile[32][33];
  const int tx = t & 31, ty = t >> 5;
  const int k0 = bx * 32, n0 = by * 32;
#pragma unroll
  for (int i = 0; i < 4; ++i) {
    int k = k0 + ty + i * 8, n = n0 + tx;
    tile[ty + i * 8][tx] = (k < K && n < N) ? W[(size_t)k * N + n] : 0.f;
  }
  __syncthreads();
#pragma unroll
  for (int i = 0; i < 4; ++i) {
    int n = n0 + ty + i * 8, k = k0 + tx;
    if (n < Npad && k < Kpad)
      Wt[(size_t)n * Kpad + k] = (bf16_t)tile[tx][ty + i * 8];
  }
}

__global__ __launch_bounds__(256) void prep_kernel(
    const float* __restrict__ y, bf16_t* __restrict__ X0,
    const float* __restrict__ eW1, bf16_t* __restrict__ W1t,
    const float* __restrict__ eW2, bf16_t* __restrict__ W2t,
    const float* __restrict__ eW3, bf16_t* __restrict__ W3t,
    const float* __restrict__ dW1, bf16_t* __restrict__ V1t,
    const float* __restrict__ dW2, bf16_t* __restrict__ V2t,
    const float* __restrict__ dW3, bf16_t* __restrict__ V3t,
    int* __restrict__ flags)
{
  const int b = blockIdx.x;
  const int t = threadIdx.x;
  if (b == 0) {          // zero queue + dependency counters (512 ints)
    for (int i = t; i < 512; i += 256) flags[i] = 0;
  }
  if (b < 16000) {
    const int idx = b * 256 + t;
    const int r = idx / 320, c = (idx % 320) * 8;
    bf16x8 v;
    if (c < 2520) {
      const float4 f0 = *(const float4*)(y + (size_t)r * 2520 + c);
      const float4 f1 = *(const float4*)(y + (size_t)r * 2520 + c + 4);
      v[0] = (bf16_t)f0.x; v[1] = (bf16_t)f0.y; v[2] = (bf16_t)f0.z; v[3] = (bf16_t)f0.w;
      v[4] = (bf16_t)f1.x; v[5] = (bf16_t)f1.y; v[6] = (bf16_t)f1.z; v[7] = (bf16_t)f1.w;
    } else {
#pragma unroll
      for (int j = 0; j < 8; ++j) v[j] = (bf16_t)0.f;
    }
    *(bf16x8*)(X0 + (size_t)r * 2560 + c) = v;
    return;
  }
  int lb = b - 16000;
  if (lb < 2560)      { transpose_tile(eW1, W1t, 2520, 1024, 2560, 1024, lb % 80, lb / 80, t); return; }
  lb -= 2560;
  if (lb < 1024)      { transpose_tile(eW2, W2t, 1024, 1024, 1024, 1024, lb % 32, lb / 32, t); return; }
  lb -= 1024;
  if (lb < 2048)      { transpose_tile(eW3, W3t, 1024, 2048, 1024, 2048, lb % 32, lb / 32, t); return; }
  lb -= 2048;
  if (lb < 2048)      { transpose_tile(dW1, V1t, 2048, 1024, 2048, 1024, lb % 64, lb / 64, t); return; }
  lb -= 2048;
  if (lb < 1024)      { transpose_tile(dW2, V2t, 1024, 1024, 1024, 1024, lb % 32, lb / 32, t); return; }
  lb -= 1024;
  transpose_tile(dW3, V3t, 1024, 2520, 1024, 2560, lb % 32, lb / 32, t);
}

// ---------------------------------------------------------------------------
// Persistent fused kernel v3: 256x128 tiles, BK=32, 2-slot dbuf, 48KB LDS
// -> 2 blocks/CU (the R6->R7 change: co-resident block hides spins/drains).
//  L0 X0@W1t->H1  L1 H1@W2t->H2  L2 H2@W3t->ze  L3 VQ(ze)->zq,ZQb
//  L4 ZQb@V1t->H3 L5 H3@V2t->H4  L6 H4@V3t->out
// Queue layer-major; deps per 256-row panel, agent-scope counters.
// Sync: relaxed poll + one acquire fence / syncthreads + release fence + add.
// ---------------------------------------------------------------------------
__global__ __launch_bounds__(512, 2) void mega_kernel(
    const bf16_t* __restrict__ X0,
    const bf16_t* __restrict__ W1t, const bf16_t* __restrict__ W2t,
    const bf16_t* __restrict__ W3t, const bf16_t* __restrict__ V1t,
    const bf16_t* __restrict__ V2t, const bf16_t* __restrict__ V3t,
    const float* __restrict__ eb1, const float* __restrict__ eb2,
    const float* __restrict__ eb3, const float* __restrict__ db1,
    const float* __restrict__ db2, const float* __restrict__ db3,
    bf16_t* __restrict__ H1, bf16_t* __restrict__ H2,
    bf16_t* __restrict__ H3, bf16_t* __restrict__ H4,
    bf16_t* __restrict__ ZQb,
    float* __restrict__ ze, float* __restrict__ zq, float* __restrict__ outp,
    const float* __restrict__ emb, int* __restrict__ flags)
{
  // slot = A 256x32 (16KB) + B 128x32 (8KB) = 24KB; 2 slots = 48KB
  __shared__ __align__(16) char smem[49152];
  __shared__ int s_idx;
  bf16_t* lds = (bf16_t*)smem;

  const int t = threadIdx.x;
  const int w = t >> 6, l = t & 63;
  const int fr = l & 15, kg = l >> 4;

  for (;;) {
    if (t == 0)
      s_idx = __hip_atomic_fetch_add(&flags[0], 1, __ATOMIC_RELAXED, __HIP_MEMORY_SCOPE_AGENT);
    __syncthreads();
    const int idx = s_idx;
    if (idx >= 3600) break;

    // ---- decode (layer, m, n); GEMM tile = 256 rows x 128 cols ----
    int layer, m, n = 0, i = idx;
    if      (i < 400)  { layer = 0;            m = i >> 3; n = i & 7; }
    else if (i < 800)  { layer = 1; i -= 400;  m = i >> 3; n = i & 7; }
    else if (i < 1600) { layer = 2; i -= 800;  m = i >> 4; n = i & 15; }
    else if (i < 1800) { layer = 3; i -= 1600; m = i; }            // VQ: 64 rows
    else if (i < 2200) { layer = 4; i -= 1800; m = i >> 3; n = i & 7; }
    else if (i < 2600) { layer = 5; i -= 2200; m = i >> 3; n = i & 7; }
    else               { layer = 6; i -= 2600; m = i / 20; n = i % 20; }

    // ---- dependency wait (relaxed poll + single acquire fence) ----
    int depl = -1, need = 0, dm = (layer == 3) ? (m >> 2) : m;
    if      (layer == 1) { depl = 0; need = 8; }
    else if (layer == 2) { depl = 1; need = 8; }
    else if (layer == 3) { depl = 2; need = 16; }
    else if (layer == 4) { depl = 3; need = 4; }
    else if (layer == 5) { depl = 4; need = 8; }
    else if (layer == 6) { depl = 5; need = 8; }
    if (need) {
      if (t == 0) {
        while (__hip_atomic_load(&flags[16 + depl * 64 + dm], __ATOMIC_RELAXED,
                                 __HIP_MEMORY_SCOPE_AGENT) < need)
          __builtin_amdgcn_s_sleep(16);
        __builtin_amdgcn_fence(__ATOMIC_ACQUIRE, "agent");
      }
      __syncthreads();
    }

    if (layer != 3) {
      // =================== GEMM tile 256x128 (2-slot dbuf) ===================
      const bf16_t* A; const bf16_t* Bt; const float* bias;
      bf16_t* Cb = nullptr; float* Cf = nullptr;
      int K, Nc, Nlog, elu;
      switch (layer) {
        case 0:  A = X0;  Bt = W1t; bias = eb1; Cb = H1; K = 2560; Nc = 1024; Nlog = 1024; elu = 1; break;
        case 1:  A = H1;  Bt = W2t; bias = eb2; Cb = H2; K = 1024; Nc = 1024; Nlog = 1024; elu = 1; break;
        case 2:  A = H2;  Bt = W3t; bias = eb3; Cf = ze; K = 1024; Nc = 2048; Nlog = 2048; elu = 0; break;
        case 4:  A = ZQb; Bt = V1t; bias = db1; Cb = H3; K = 2048; Nc = 1024; Nlog = 1024; elu = 1; break;
        case 5:  A = H3;  Bt = V2t; bias = db2; Cb = H4; K = 1024; Nc = 1024; Nlog = 1024; elu = 1; break;
        default: A = H4;  Bt = V3t; bias = db3; Cf = outp; K = 1024; Nc = 2560; Nlog = 2520; elu = 0; break;
      }
      const int tm = m * 256, tn = n * 128;
      const int wm = (w >> 1) * 64, wn = (w & 1) * 64;   // 4M x 2N waves, 64x64 each
      const int srow = t >> 2, scol = (t & 3) * 8, sdst = t * 8;
      const int NT = K >> 5;

      f32x4 acc[4][4];
#pragma unroll
      for (int a = 0; a < 4; ++a)
#pragma unroll
        for (int b = 0; b < 4; ++b) acc[a][b] = (f32x4){0.f, 0.f, 0.f, 0.f};

      // slot elems: 12288 (A 8192 + B 4096)
      auto stageAB = [&](int slot, int kn) {
        bf16_t* d = lds + slot * 12288;
        gl_lds16(A  + (size_t)(tm + srow) * K + kn + scol,       d + sdst);
        gl_lds16(A  + (size_t)(tm + 128 + srow) * K + kn + scol, d + 4096 + sdst);
        gl_lds16(Bt + (size_t)(tn + (t >> 2)) * K + kn + scol,   d + 8192 + sdst);
      };

      stageAB(0, 0);
      asm volatile("s_waitcnt vmcnt(0)" ::: "memory");
      BAR();

      for (int kt = 0; kt < NT; ++kt) {
        const int s = kt & 1;
        const bf16_t* aH = lds + s * 12288 + wm * 32;
        const bf16_t* bH = lds + s * 12288 + 8192 + wn * 32;
        const bool pf = (kt + 1 < NT);

        bf16x8 af[4], bf_[4];
#pragma unroll
        for (int mi = 0; mi < 4; ++mi)
          af[mi] = *(const bf16x8*)(aH + (mi * 16 + fr) * 32 + kg * 8);
#pragma unroll
        for (int nj = 0; nj < 4; ++nj)
          bf_[nj] = *(const bf16x8*)(bH + (nj * 16 + fr) * 32 + kg * 8);
        if (pf) stageAB(s ^ 1, (kt + 1) << 5);
        LGK0();
        __builtin_amdgcn_s_setprio(1);
#pragma unroll
        for (int mi = 0; mi < 4; ++mi)
#pragma unroll
          for (int nj = 0; nj < 4; ++nj)
            acc[mi][nj] = __builtin_amdgcn_mfma_f32_16x16x32_bf16(af[mi], bf_[nj], acc[mi][nj], 0, 0, 0);
        __builtin_amdgcn_s_setprio(0);
        asm volatile("s_waitcnt vmcnt(0)" ::: "memory");  // next slot resident
        BAR();                                            // all waves: reads done, loads done
      }

#pragma unroll
      for (int mi = 0; mi < 4; ++mi) {
        const int row0 = tm + wm + mi * 16 + kg * 4;
#pragma unroll
        for (int nj = 0; nj < 4; ++nj) {
          const int col = tn + wn + nj * 16 + fr;
          const float bv = (col < Nlog) ? bias[col] : 0.f;
#pragma unroll
          for (int r = 0; r < 4; ++r) {
            float v = acc[mi][nj][r] + bv;
            if (elu && v <= 0.f) v = expm1f(v);
            const int row = row0 + r;
            if (Cb) Cb[(size_t)row * Nc + col] = (bf16_t)v;
            if (Cf && col < Nlog) Cf[(size_t)row * Nlog + col] = v;
          }
        }
      }
    } else {
      // =================== VQ tile: 64 rows of ze ===================
      float*  se  = (float*)smem;          // 2048 f32
      bf16_t* seb = (bf16_t*)(smem + 8192);
      for (int q = t; q < 2048; q += 512) { float v = emb[q]; se[q] = v; seb[q] = (bf16_t)v; }
      __syncthreads();

      const int col = l & 15;
      const int ks8 = (l >> 4) * 8;
      const bool kact = (ks8 < 16);

      bf16x8 bfrag[8];
      float  hv[8];
#pragma unroll
      for (int cb = 0; cb < 8; ++cb) {
        float s = 0.f;
        bf16x8 bf;
#pragma unroll
        for (int j = 0; j < 8; ++j) bf[j] = (bf16_t)0.f;
        if (kact) {
          const float* ep = se + (cb * 16 + col) * 16 + ks8;
          float4 e0 = *(const float4*)ep;
          float4 e1 = *(const float4*)(ep + 4);
          bf[0] = (bf16_t)e0.x; bf[1] = (bf16_t)e0.y; bf[2] = (bf16_t)e0.z; bf[3] = (bf16_t)e0.w;
          bf[4] = (bf16_t)e1.x; bf[5] = (bf16_t)e1.y; bf[6] = (bf16_t)e1.z; bf[7] = (bf16_t)e1.w;
          s = e0.x*e0.x + e0.y*e0.y + e0.z*e0.z + e0.w*e0.w
            + e1.x*e1.x + e1.y*e1.y + e1.z*e1.z + e1.w*e1.w;
        }
        s += __shfl_xor(s, 16);
        s += __shfl_xor(s, 32);
        bfrag[cb] = bf;
        hv[cb] = 0.5f * s;
      }

      const int rbase = m * 64;
      for (int it = 0; it < 64; ++it) {
        const int wt = w * 64 + it;                 // 0..511
        const int row = rbase + (wt >> 3);
        const int g0 = (wt & 7) * 16;

        bf16x8 afrag;
#pragma unroll
        for (int j = 0; j < 8; ++j) afrag[j] = (bf16_t)0.f;
        if (kact) {
          const float* ap = ze + (size_t)row * 2048 + (g0 + col) * 16 + ks8;
          float4 a0 = *(const float4*)ap;
          float4 a1 = *(const float4*)(ap + 4);
          afrag[0] = (bf16_t)(-a0.x); afrag[1] = (bf16_t)(-a0.y);
          afrag[2] = (bf16_t)(-a0.z); afrag[3] = (bf16_t)(-a0.w);
          afrag[4] = (bf16_t)(-a1.x); afrag[5] = (bf16_t)(-a1.y);
          afrag[6] = (bf16_t)(-a1.z); afrag[7] = (bf16_t)(-a1.w);
        }

        f32x4 dd[8];
#pragma unroll
        for (int cb = 0; cb < 8; ++cb) {
          f32x4 c = (f32x4){hv[cb], hv[cb], hv[cb], hv[cb]};
          dd[cb] = __builtin_amdgcn_mfma_f32_16x16x32_bf16(afrag, bfrag[cb], c, 0, 0, 0);
        }

#pragma unroll
        for (int r = 0; r < 4; ++r) {
          float bd = dd[0][r]; int bi = col;
#pragma unroll
          for (int cb = 1; cb < 8; ++cb) {
            float v = dd[cb][r];
            int   ci = cb * 16 + col;
            if (v < bd) { bd = v; bi = ci; }
          }
#pragma unroll
          for (int mm = 1; mm < 16; mm <<= 1) {
            float od = __shfl_xor(bd, mm);
            int   oi = __shfl_xor(bi, mm);
            if (od < bd || (od == bd && oi < bi)) { bd = od; bi = oi; }
          }
          if (col == r) {
            const int tok = (l >> 4) * 4 + r;
            const size_t go = ((size_t)row * 128 + g0 + tok) * 16;
            const float*  e  = se  + bi * 16;
            const bf16_t* eb = seb + bi * 16;
#pragma unroll
            for (int v = 0; v < 4; ++v)
              *(float4*)(zq + go + v * 4) = ((const float4*)e)[v];
            *(bf16x8*)(ZQb + go)     = ((const bf16x8*)eb)[0];
            *(bf16x8*)(ZQb + go + 8) = ((const bf16x8*)eb)[1];
          }
        }
      }
    }

    // ---- publish: drain stores, then ONE release fence + relaxed add on t0 ----
    asm volatile("s_waitcnt vmcnt(0) lgkmcnt(0)" ::: "memory");
    __syncthreads();
    if (t == 0 && layer != 6) {
      const int pm = (layer == 3) ? (m >> 2) : m;
      __builtin_amdgcn_fence(__ATOMIC_RELEASE, "agent");
      __hip_atomic_fetch_add(&flags[16 + layer * 64 + pm], 1, __ATOMIC_RELAXED,
                             __HIP_MEMORY_SCOPE_AGENT);
    }
  }
}

// ---------------------------------------------------------------------------
extern "C" void kernel_launch(void* const* d_in, const int* in_sizes, int n_in,
                              void* d_out, int out_size, void* d_ws, size_t ws_size,
                              hipStream_t stream)
{
  const float* y   = (const float*)d_in[0];
  const float* emb = (const float*)d_in[1];
  const float* eW1 = (const float*)d_in[2];
  const float* eb1 = (const float*)d_in[3];
  const float* eW2 = (const float*)d_in[4];
  const float* eb2 = (const float*)d_in[5];
  const float* eW3 = (const float*)d_in[6];
  const float* eb3 = (const float*)d_in[7];
  const float* dW1 = (const float*)d_in[8];
  const float* db1 = (const float*)d_in[9];
  const float* dW2 = (const float*)d_in[10];
  const float* db2 = (const float*)d_in[11];
  const float* dW3 = (const float*)d_in[12];
  const float* db3 = (const float*)d_in[13];

  float* out = (float*)d_out;               // [12800][2520]
  float* ze  = out + 32256000;              // [12800][2048]
  float* zq  = ze + 26214400;               // [12800][2048]

  uint8_t* ws = (uint8_t*)d_ws;
  size_t off = 0;
  auto alloc = [&](size_t bytes) -> void* {
    void* p = ws + off; off += (bytes + 255) & ~(size_t)255; return p;
  };
  bf16_t* X0  = (bf16_t*)alloc(12800ULL * 2560 * 2);
  bf16_t* W1t = (bf16_t*)alloc(1024ULL * 2560 * 2);
  bf16_t* W2t = (bf16_t*)alloc(1024ULL * 1024 * 2);
  bf16_t* W3t = (bf16_t*)alloc(2048ULL * 1024 * 2);
  bf16_t* V1t = (bf16_t*)alloc(1024ULL * 2048 * 2);
  bf16_t* V2t = (bf16_t*)alloc(1024ULL * 1024 * 2);
  bf16_t* V3t = (bf16_t*)alloc(2560ULL * 1024 * 2);
  bf16_t* H1  = (bf16_t*)alloc(12800ULL * 1024 * 2);
  bf16_t* H2  = (bf16_t*)alloc(12800ULL * 1024 * 2);
  bf16_t* H3  = (bf16_t*)alloc(12800ULL * 1024 * 2);
  bf16_t* H4  = (bf16_t*)alloc(12800ULL * 1024 * 2);
  bf16_t* ZQb = (bf16_t*)alloc(12800ULL * 2048 * 2);
  int*    flags = (int*)alloc(512 * 4);

  prep_kernel<<<27264, 256, 0, stream>>>(y, X0, eW1, W1t, eW2, W2t, eW3, W3t,
                                         dW1, V1t, dW2, V2t, dW3, V3t, flags);

  mega_kernel<<<512, 512, 0, stream>>>(X0, W1t, W2t, W3t, V1t, V2t, V3t,
                                       eb1, eb2, eb3, db1, db2, db3,
                                       H1, H2, H3, H4, ZQb,
                                       ze, zq, out, emb, flags);
}

// Round 8
// 643.638 us; speedup vs baseline: 1.3067x; 1.3067x over previous
//
#include <hip/hip_runtime.h>
#include <hip/hip_bf16.h>
#include <cstdint>
#include <cstddef>

typedef __bf16 bf16_t;
typedef bf16_t bf16x8 __attribute__((ext_vector_type(8)));
typedef float  f32x4  __attribute__((ext_vector_type(4)));

__device__ __forceinline__ void gl_lds16(const void* g, void* l) {
  __builtin_amdgcn_global_load_lds(
      (const __attribute__((address_space(1))) void*)g,
      (__attribute__((address_space(3))) void*)l, 16, 0, 0);
}

#define BAR()  __builtin_amdgcn_s_barrier()
#define LGK0() asm volatile("s_waitcnt lgkmcnt(0)" ::: "memory")

// ---------------------------------------------------------------------------
// prep kernel: fused pack_x0 + 6 weight transposes (fp32 -> bf16, KxN -> Npad x Kpad)
// ---------------------------------------------------------------------------
__device__ __forceinline__ void transpose_tile(
    const float* __restrict__ W, bf16_t* __restrict__ Wt,
    int K, int N, int Kpad, int Npad, int bx, int by, int t)
{
  __shared__ float tile[32][33];
  const int tx = t & 31, ty = t >> 5;
  const int k0 = bx * 32, n0 = by * 32;
#pragma unroll
  for (int i = 0; i < 4; ++i) {
    int k = k0 + ty + i * 8, n = n0 + tx;
    tile[ty + i * 8][tx] = (k < K && n < N) ? W[(size_t)k * N + n] : 0.f;
  }
  __syncthreads();
#pragma unroll
  for (int i = 0; i < 4; ++i) {
    int n = n0 + ty + i * 8, k = k0 + tx;
    if (n < Npad && k < Kpad)
      Wt[(size_t)n * Kpad + k] = (bf16_t)tile[tx][ty + i * 8];
  }
}

__global__ __launch_bounds__(256) void prep_kernel(
    const float* __restrict__ y, bf16_t* __restrict__ X0,
    const float* __restrict__ eW1, bf16_t* __restrict__ W1t,
    const float* __restrict__ eW2, bf16_t* __restrict__ W2t,
    const float* __restrict__ eW3, bf16_t* __restrict__ W3t,
    const float* __restrict__ dW1, bf16_t* __restrict__ V1t,
    const float* __restrict__ dW2, bf16_t* __restrict__ V2t,
    const float* __restrict__ dW3, bf16_t* __restrict__ V3t)
{
  const int b = blockIdx.x;
  const int t = threadIdx.x;
  if (b < 16000) {
    const int idx = b * 256 + t;
    const int r = idx / 320, c = (idx % 320) * 8;
    bf16x8 v;
    if (c < 2520) {
      const float4 f0 = *(const float4*)(y + (size_t)r * 2520 + c);
      const float4 f1 = *(const float4*)(y + (size_t)r * 2520 + c + 4);
      v[0] = (bf16_t)f0.x; v[1] = (bf16_t)f0.y; v[2] = (bf16_t)f0.z; v[3] = (bf16_t)f0.w;
      v[4] = (bf16_t)f1.x; v[5] = (bf16_t)f1.y; v[6] = (bf16_t)f1.z; v[7] = (bf16_t)f1.w;
    } else {
#pragma unroll
      for (int j = 0; j < 8; ++j) v[j] = (bf16_t)0.f;
    }
    *(bf16x8*)(X0 + (size_t)r * 2560 + c) = v;
    return;
  }
  int lb = b - 16000;
  if (lb < 2560)      { transpose_tile(eW1, W1t, 2520, 1024, 2560, 1024, lb % 80, lb / 80, t); return; }
  lb -= 2560;
  if (lb < 1024)      { transpose_tile(eW2, W2t, 1024, 1024, 1024, 1024, lb % 32, lb / 32, t); return; }
  lb -= 1024;
  if (lb < 2048)      { transpose_tile(eW3, W3t, 1024, 2048, 1024, 2048, lb % 32, lb / 32, t); return; }
  lb -= 2048;
  if (lb < 2048)      { transpose_tile(dW1, V1t, 2048, 1024, 2048, 1024, lb % 64, lb / 64, t); return; }
  lb -= 2048;
  if (lb < 1024)      { transpose_tile(dW2, V2t, 1024, 1024, 1024, 1024, lb % 32, lb / 32, t); return; }
  lb -= 1024;
  transpose_tile(dW3, V3t, 1024, 2520, 1024, 2560, lb % 32, lb / 32, t);
}

// ---------------------------------------------------------------------------
// 256x256 GEMM, BK=32, 4 LDS slots, depth-3 prefetch, counted vmcnt(8),
// SINGLE phase per K-tile (R8 change): stage-first, 12 ds_reads, one lgkmcnt,
// 32-MFMA cluster under setprio, vmcnt(8), ONE barrier.
// 8 waves (2M x 4N), wave tile 128x64. LDS 4 x 32KB = 128KB.
// C[M][N] = A[M][K] @ Bt[N][K]^T + bias, optional ELU.
// Requires M%256==0, N%256==0, K%32==0, K/32 >= 4.
// ---------------------------------------------------------------------------
template<int ELU>
__global__ __launch_bounds__(512, 2) void gemm256(
    const bf16_t* __restrict__ A, const bf16_t* __restrict__ Bt,
    const float* __restrict__ bias,
    bf16_t* __restrict__ Cb, float* __restrict__ Cf,
    int M, int N, int K, int Nlog)
{
  __shared__ __align__(16) bf16_t lds[65536];   // 4 x 16384 elems

  const int t  = threadIdx.x;
  const int w  = t >> 6, l = t & 63;
  const int fr = l & 15, kg = l >> 4;
  const int wm = (w >> 2) * 128, wn = (w & 3) * 64;   // 2M x 4N waves

  // bijective XCD-aware remap (m204)
  const int gx = gridDim.x;
  const int nwg = gx * (int)gridDim.y;
  int lin = blockIdx.y * gx + blockIdx.x;
  int q8 = nwg >> 3, r8 = nwg & 7, xcd = lin & 7, idx = lin >> 3;
  int swz = (xcd < r8 ? xcd * (q8 + 1) : r8 * (q8 + 1) + (xcd - r8) * q8) + idx;
  const int tn = (swz % gx) * 256;
  const int tm = (swz / gx) * 256;

  // staging: per K-tile, A chunk (256x32) and B chunk (256x32), 2 x 16B/thread each.
  const int srow = t >> 2;
  const int scol = (t & 3) * 8;
  const int sdst = t * 8;

  const int NT = K >> 5;

  f32x4 acc[8][4];
#pragma unroll
  for (int i = 0; i < 8; ++i)
#pragma unroll
    for (int j = 0; j < 4; ++j) acc[i][j] = (f32x4){0.f, 0.f, 0.f, 0.f};

  auto stageA = [&](int slot, int kn) {
    bf16_t* d = lds + slot * 16384;
    gl_lds16(A + (size_t)(tm + srow) * K + kn + scol,       d + sdst);
    gl_lds16(A + (size_t)(tm + 128 + srow) * K + kn + scol, d + 4096 + sdst);
  };
  auto stageB = [&](int slot, int kn) {
    bf16_t* d = lds + slot * 16384 + 8192;
    gl_lds16(Bt + (size_t)(tn + srow) * K + kn + scol,       d + sdst);
    gl_lds16(Bt + (size_t)(tn + 128 + srow) * K + kn + scol, d + 4096 + sdst);
  };

  // prologue: stage tiles 0,1,2; wait so tile 0 (oldest 4 loads) is resident.
  stageA(0, 0);  stageB(0, 0);
  stageA(1, 32); stageB(1, 32);
  stageA(2, 64); stageB(2, 64);
  asm volatile("s_waitcnt vmcnt(8)" ::: "memory");
  BAR();

  for (int kt = 0; kt < NT; ++kt) {
    const int slot = kt & 3;
    const bf16_t* aH = lds + slot * 16384 + wm * 32;          // wave's 128-row A view
    const bf16_t* bH = lds + slot * 16384 + 8192 + wn * 32;   // wave's 64-row B view
    const bool pf = (kt + 3 < NT);
    const int ps = (kt + 3) & 3;
    const int kn = (kt + 3) << 5;

    // issue next tile's staging first (T14: HBM latency hides under this tile)
    if (pf) { stageA(ps, kn); stageB(ps, kn); }

    bf16x8 af[8], bf_[4];
#pragma unroll
    for (int mi = 0; mi < 8; ++mi)
      af[mi] = *(const bf16x8*)(aH + (mi * 16 + fr) * 32 + kg * 8);
#pragma unroll
    for (int nj = 0; nj < 4; ++nj)
      bf_[nj] = *(const bf16x8*)(bH + (nj * 16 + fr) * 32 + kg * 8);
    LGK0();
    __builtin_amdgcn_s_setprio(1);
#pragma unroll
    for (int mi = 0; mi < 8; ++mi)
#pragma unroll
      for (int nj = 0; nj < 4; ++nj)
        acc[mi][nj] = __builtin_amdgcn_mfma_f32_16x16x32_bf16(af[mi], bf_[nj], acc[mi][nj], 0, 0, 0);
    __builtin_amdgcn_s_setprio(0);
    // after wait: outstanding = tiles kt+2,kt+3 (8 loads) -> tile kt+1 resident
    asm volatile("s_waitcnt vmcnt(8)" ::: "memory");
    BAR();
  }

  // epilogue: C/D layout col = lane&15, row = (lane>>4)*4 + reg
#pragma unroll
  for (int mi = 0; mi < 8; ++mi) {
    const int row0 = tm + wm + mi * 16 + kg * 4;
#pragma unroll
    for (int nj = 0; nj < 4; ++nj) {
      const int col = tn + wn + nj * 16 + fr;
      const float bv = (col < Nlog) ? bias[col] : 0.f;
#pragma unroll
      for (int r = 0; r < 4; ++r) {
        float v = acc[mi][nj][r] + bv;
        if (ELU) v = (v > 0.f) ? v : expm1f(v);
        const int row = row0 + r;
        if (Cb) Cb[(size_t)row * N + col] = (bf16_t)v;
        if (Cf && col < Nlog) Cf[(size_t)row * Nlog + col] = v;
      }
    }
  }
}

// ---------------------------------------------------------------------------
// MFMA VQ: d = 0.5*||e||^2 - <z,e> via 16x16x32 bf16 MFMA (K padded with 0s).
// ---------------------------------------------------------------------------
__global__ __launch_bounds__(256) void vq_mfma(
    const float* __restrict__ ze, const float* __restrict__ emb,
    float* __restrict__ zq, bf16_t* __restrict__ zqb)
{
  __shared__ float  se[2048];
  __shared__ bf16_t seb[2048];
  const int t = threadIdx.x;
  for (int i = t; i < 2048; i += 256) { float v = emb[i]; se[i] = v; seb[i] = (bf16_t)v; }
  __syncthreads();

  const int l = t & 63, w = t >> 6;
  const int col = l & 15;
  const int ks8 = (l >> 4) * 8;
  const bool kact = (ks8 < 16);

  bf16x8 bfrag[8];
  float  hv[8];
#pragma unroll
  for (int cb = 0; cb < 8; ++cb) {
    float s = 0.f;
    bf16x8 bf;
#pragma unroll
    for (int j = 0; j < 8; ++j) bf[j] = (bf16_t)0.f;
    if (kact) {
      const float* ep = se + (cb * 16 + col) * 16 + ks8;
      float4 e0 = *(const float4*)ep;
      float4 e1 = *(const float4*)(ep + 4);
      bf[0] = (bf16_t)e0.x; bf[1] = (bf16_t)e0.y; bf[2] = (bf16_t)e0.z; bf[3] = (bf16_t)e0.w;
      bf[4] = (bf16_t)e1.x; bf[5] = (bf16_t)e1.y; bf[6] = (bf16_t)e1.z; bf[7] = (bf16_t)e1.w;
      s = e0.x*e0.x + e0.y*e0.y + e0.z*e0.z + e0.w*e0.w
        + e1.x*e1.x + e1.y*e1.y + e1.z*e1.z + e1.w*e1.w;
    }
    s += __shfl_xor(s, 16);
    s += __shfl_xor(s, 32);
    bfrag[cb] = bf;
    hv[cb] = 0.5f * s;
  }

  const int base_tile = blockIdx.x * 64 + w * 16;
  for (int it = 0; it < 16; ++it) {
    const int tile = base_tile + it;
    const int row = tile >> 3, g0 = (tile & 7) * 16;

    bf16x8 afrag;
#pragma unroll
    for (int j = 0; j < 8; ++j) afrag[j] = (bf16_t)0.f;
    if (kact) {
      const float* ap = ze + (size_t)row * 2048 + (g0 + col) * 16 + ks8;
      float4 a0 = *(const float4*)ap;
      float4 a1 = *(const float4*)(ap + 4);
      afrag[0] = (bf16_t)(-a0.x); afrag[1] = (bf16_t)(-a0.y);
      afrag[2] = (bf16_t)(-a0.z); afrag[3] = (bf16_t)(-a0.w);
      afrag[4] = (bf16_t)(-a1.x); afrag[5] = (bf16_t)(-a1.y);
      afrag[6] = (bf16_t)(-a1.z); afrag[7] = (bf16_t)(-a1.w);
    }

    f32x4 dd[8];
#pragma unroll
    for (int cb = 0; cb < 8; ++cb) {
      f32x4 c = (f32x4){hv[cb], hv[cb], hv[cb], hv[cb]};
      dd[cb] = __builtin_amdgcn_mfma_f32_16x16x32_bf16(afrag, bfrag[cb], c, 0, 0, 0);
    }

#pragma unroll
    for (int r = 0; r < 4; ++r) {
      float bd = dd[0][r]; int bi = col;
#pragma unroll
      for (int cb = 1; cb < 8; ++cb) {
        float v = dd[cb][r];
        int   ci = cb * 16 + col;
        if (v < bd) { bd = v; bi = ci; }
      }
#pragma unroll
      for (int m = 1; m < 16; m <<= 1) {
        float od = __shfl_xor(bd, m);
        int   oi = __shfl_xor(bi, m);
        if (od < bd || (od == bd && oi < bi)) { bd = od; bi = oi; }
      }
      if (col == r) {
        const int tok = (l >> 4) * 4 + r;
        const size_t go = ((size_t)row * 128 + g0 + tok) * 16;
        const float*  e  = se  + bi * 16;
        const bf16_t* eb = seb + bi * 16;
#pragma unroll
        for (int v = 0; v < 4; ++v)
          *(float4*)(zq + go + v * 4) = ((const float4*)e)[v];
        *(bf16x8*)(zqb + go)     = ((const bf16x8*)eb)[0];
        *(bf16x8*)(zqb + go + 8) = ((const bf16x8*)eb)[1];
      }
    }
  }
}

// ---------------------------------------------------------------------------
extern "C" void kernel_launch(void* const* d_in, const int* in_sizes, int n_in,
                              void* d_out, int out_size, void* d_ws, size_t ws_size,
                              hipStream_t stream)
{
  const float* y   = (const float*)d_in[0];
  const float* emb = (const float*)d_in[1];
  const float* eW1 = (const float*)d_in[2];
  const float* eb1 = (const float*)d_in[3];
  const float* eW2 = (const float*)d_in[4];
  const float* eb2 = (const float*)d_in[5];
  const float* eW3 = (const float*)d_in[6];
  const float* eb3 = (const float*)d_in[7];
  const float* dW1 = (const float*)d_in[8];
  const float* db1 = (const float*)d_in[9];
  const float* dW2 = (const float*)d_in[10];
  const float* db2 = (const float*)d_in[11];
  const float* dW3 = (const float*)d_in[12];
  const float* db3 = (const float*)d_in[13];

  float* out = (float*)d_out;               // [12800][2520]
  float* ze  = out + 32256000;              // [12800][2048]
  float* zq  = ze + 26214400;               // [12800][2048]

  uint8_t* ws = (uint8_t*)d_ws;
  size_t off = 0;
  auto alloc = [&](size_t bytes) -> void* {
    void* p = ws + off; off += (bytes + 255) & ~(size_t)255; return p;
  };
  bf16_t* X0  = (bf16_t*)alloc(12800ULL * 2560 * 2);
  bf16_t* W1t = (bf16_t*)alloc(1024ULL * 2560 * 2);
  bf16_t* W2t = (bf16_t*)alloc(1024ULL * 1024 * 2);
  bf16_t* W3t = (bf16_t*)alloc(2048ULL * 1024 * 2);
  bf16_t* V1t = (bf16_t*)alloc(1024ULL * 2048 * 2);
  bf16_t* V2t = (bf16_t*)alloc(1024ULL * 1024 * 2);
  bf16_t* V3t = (bf16_t*)alloc(2560ULL * 1024 * 2);
  bf16_t* H1  = (bf16_t*)alloc(12800ULL * 1024 * 2);
  bf16_t* H2  = (bf16_t*)alloc(12800ULL * 1024 * 2);
  bf16_t* ZQb = (bf16_t*)alloc(12800ULL * 2048 * 2);

  prep_kernel<<<27264, 256, 0, stream>>>(y, X0, eW1, W1t, eW2, W2t, eW3, W3t,
                                         dW1, V1t, dW2, V2t, dW3, V3t);

  // encoder
  gemm256<1><<<dim3(4, 50), 512, 0, stream>>>(X0, W1t, eb1, H1, nullptr, 12800, 1024, 2560, 1024);
  gemm256<1><<<dim3(4, 50), 512, 0, stream>>>(H1, W2t, eb2, H2, nullptr, 12800, 1024, 1024, 1024);
  gemm256<0><<<dim3(8, 50), 512, 0, stream>>>(H2, W3t, eb3, nullptr, ze, 12800, 2048, 1024, 2048);
  // vector quantize
  vq_mfma<<<1600, 256, 0, stream>>>(ze, emb, zq, ZQb);
  // decoder
  gemm256<1><<<dim3(4, 50), 512, 0, stream>>>(ZQb, V1t, db1, H1, nullptr, 12800, 1024, 2048, 1024);
  gemm256<1><<<dim3(4, 50), 512, 0, stream>>>(H1, V2t, db2, H2, nullptr, 12800, 1024, 1024, 1024);
  gemm256<0><<<dim3(10, 50), 512, 0, stream>>>(H2, V3t, db3, nullptr, out, 12800, 2560, 1024, 2520);
}

// Round 9
// 613.704 us; speedup vs baseline: 1.3704x; 1.0488x over previous
//
#include <hip/hip_runtime.h>
#include <hip/hip_bf16.h>
#include <cstdint>
#include <cstddef>

typedef __bf16 bf16_t;
typedef bf16_t bf16x8 __attribute__((ext_vector_type(8)));
typedef float  f32x4  __attribute__((ext_vector_type(4)));

__device__ __forceinline__ void gl_lds16(const void* g, void* l) {
  __builtin_amdgcn_global_load_lds(
      (const __attribute__((address_space(1))) void*)g,
      (__attribute__((address_space(3))) void*)l, 16, 0, 0);
}

#define BAR()  __builtin_amdgcn_s_barrier()
#define LGK0() asm volatile("s_waitcnt lgkmcnt(0)" ::: "memory")

// ---------------------------------------------------------------------------
// prep kernel: fused pack_x0 + 6 weight transposes (fp32 -> bf16, KxN -> Npad x Kpad)
// ---------------------------------------------------------------------------
__device__ __forceinline__ void transpose_tile(
    const float* __restrict__ W, bf16_t* __restrict__ Wt,
    int K, int N, int Kpad, int Npad, int bx, int by, int t)
{
  __shared__ float tile[32][33];
  const int tx = t & 31, ty = t >> 5;
  const int k0 = bx * 32, n0 = by * 32;
#pragma unroll
  for (int i = 0; i < 4; ++i) {
    int k = k0 + ty + i * 8, n = n0 + tx;
    tile[ty + i * 8][tx] = (k < K && n < N) ? W[(size_t)k * N + n] : 0.f;
  }
  __syncthreads();
#pragma unroll
  for (int i = 0; i < 4; ++i) {
    int n = n0 + ty + i * 8, k = k0 + tx;
    if (n < Npad && k < Kpad)
      Wt[(size_t)n * Kpad + k] = (bf16_t)tile[tx][ty + i * 8];
  }
}

__global__ __launch_bounds__(256) void prep_kernel(
    const float* __restrict__ y, bf16_t* __restrict__ X0,
    const float* __restrict__ eW1, bf16_t* __restrict__ W1t,
    const float* __restrict__ eW2, bf16_t* __restrict__ W2t,
    const float* __restrict__ eW3, bf16_t* __restrict__ W3t,
    const float* __restrict__ dW1, bf16_t* __restrict__ V1t,
    const float* __restrict__ dW2, bf16_t* __restrict__ V2t,
    const float* __restrict__ dW3, bf16_t* __restrict__ V3t)
{
  const int b = blockIdx.x;
  const int t = threadIdx.x;
  if (b < 16000) {
    const int idx = b * 256 + t;
    const int r = idx / 320, c = (idx % 320) * 8;
    bf16x8 v;
    if (c < 2520) {
      const float4 f0 = *(const float4*)(y + (size_t)r * 2520 + c);
      const float4 f1 = *(const float4*)(y + (size_t)r * 2520 + c + 4);
      v[0] = (bf16_t)f0.x; v[1] = (bf16_t)f0.y; v[2] = (bf16_t)f0.z; v[3] = (bf16_t)f0.w;
      v[4] = (bf16_t)f1.x; v[5] = (bf16_t)f1.y; v[6] = (bf16_t)f1.z; v[7] = (bf16_t)f1.w;
    } else {
#pragma unroll
      for (int j = 0; j < 8; ++j) v[j] = (bf16_t)0.f;
    }
    *(bf16x8*)(X0 + (size_t)r * 2560 + c) = v;
    return;
  }
  int lb = b - 16000;
  if (lb < 2560)      { transpose_tile(eW1, W1t, 2520, 1024, 2560, 1024, lb % 80, lb / 80, t); return; }
  lb -= 2560;
  if (lb < 1024)      { transpose_tile(eW2, W2t, 1024, 1024, 1024, 1024, lb % 32, lb / 32, t); return; }
  lb -= 1024;
  if (lb < 2048)      { transpose_tile(eW3, W3t, 1024, 2048, 1024, 2048, lb % 32, lb / 32, t); return; }
  lb -= 2048;
  if (lb < 2048)      { transpose_tile(dW1, V1t, 2048, 1024, 2048, 1024, lb % 64, lb / 64, t); return; }
  lb -= 2048;
  if (lb < 1024)      { transpose_tile(dW2, V2t, 1024, 1024, 1024, 1024, lb % 32, lb / 32, t); return; }
  lb -= 1024;
  transpose_tile(dW3, V3t, 1024, 2520, 1024, 2560, lb % 32, lb / 32, t);
}

// ---------------------------------------------------------------------------
// 256x128 GEMM, BK=32, 3 LDS slots (72KB), depth-2 prefetch, counted vmcnt(3),
// single phase per K-tile, TWO blocks per CU (launch_bounds 512,4).
// 8 waves (4M x 2N), wave tile 64x64, 16 MFMA 16x16x32 per K-tile per wave.
// C[M][N] = A[M][K] @ Bt[N][K]^T + bias, optional ELU.
// Requires M%256==0, N%128==0, K%32==0, K/32 >= 2.
// ---------------------------------------------------------------------------
template<int ELU>
__global__ __launch_bounds__(512, 4) void gemm128(
    const bf16_t* __restrict__ A, const bf16_t* __restrict__ Bt,
    const float* __restrict__ bias,
    bf16_t* __restrict__ Cb, float* __restrict__ Cf,
    int M, int N, int K, int Nlog)
{
  // slot = A 256x32 (8192 el) + B 128x32 (4096 el) = 12288 el = 24KB; 3 slots
  __shared__ __align__(16) bf16_t lds[36864];

  const int t  = threadIdx.x;
  const int w  = t >> 6, l = t & 63;
  const int fr = l & 15, kg = l >> 4;
  const int wm = (w >> 1) * 64, wn = (w & 1) * 64;   // 4M x 2N waves

  // bijective XCD-aware remap (m204)
  const int gx = gridDim.x;
  const int nwg = gx * (int)gridDim.y;
  int lin = blockIdx.y * gx + blockIdx.x;
  int q8 = nwg >> 3, r8 = nwg & 7, xcd = lin & 7, idx = lin >> 3;
  int swz = (xcd < r8 ? xcd * (q8 + 1) : r8 * (q8 + 1) + (xcd - r8) * q8) + idx;
  const int tn = (swz % gx) * 128;
  const int tm = (swz / gx) * 256;

  const int srow = t >> 2;          // A: 0..127 (two halves); B: 0..127
  const int scol = (t & 3) * 8;
  const int sdst = t * 8;

  const int NT = K >> 5;

  f32x4 acc[4][4];
#pragma unroll
  for (int i = 0; i < 4; ++i)
#pragma unroll
    for (int j = 0; j < 4; ++j) acc[i][j] = (f32x4){0.f, 0.f, 0.f, 0.f};

  auto stage = [&](int slot, int kn) {
    bf16_t* d = lds + slot * 12288;
    gl_lds16(A  + (size_t)(tm + srow) * K + kn + scol,       d + sdst);
    gl_lds16(A  + (size_t)(tm + 128 + srow) * K + kn + scol, d + 4096 + sdst);
    gl_lds16(Bt + (size_t)(tn + srow) * K + kn + scol,       d + 8192 + sdst);
  };

  // prologue: stage tiles 0,1; wait for tile 0 (leave tile 1's 3 in flight).
  stage(0, 0);
  stage(1, 32);
  asm volatile("s_waitcnt vmcnt(3)" ::: "memory");
  BAR();

  for (int kt = 0; kt < NT; ++kt) {
    const int slot = kt % 3;
    const bf16_t* aH = lds + slot * 12288 + wm * 32;          // wave's 64-row A view
    const bf16_t* bH = lds + slot * 12288 + 8192 + wn * 32;   // wave's 64-row B view

    // stage tile kt+2 (slot (kt+2)%3: last read at tile kt-1, drained)
    if (kt + 2 < NT) stage((kt + 2) % 3, (kt + 2) << 5);

    bf16x8 af[4], bf_[4];
#pragma unroll
    for (int mi = 0; mi < 4; ++mi)
      af[mi] = *(const bf16x8*)(aH + (mi * 16 + fr) * 32 + kg * 8);
#pragma unroll
    for (int nj = 0; nj < 4; ++nj)
      bf_[nj] = *(const bf16x8*)(bH + (nj * 16 + fr) * 32 + kg * 8);
    LGK0();
    __builtin_amdgcn_s_setprio(1);
#pragma unroll
    for (int mi = 0; mi < 4; ++mi)
#pragma unroll
      for (int nj = 0; nj < 4; ++nj)
        acc[mi][nj] = __builtin_amdgcn_mfma_f32_16x16x32_bf16(af[mi], bf_[nj], acc[mi][nj], 0, 0, 0);
    __builtin_amdgcn_s_setprio(0);
    // leave tile kt+2's 3 loads in flight -> tile kt+1 resident
    asm volatile("s_waitcnt vmcnt(3)" ::: "memory");
    BAR();
  }

  // epilogue: C/D layout col = lane&15, row = (lane>>4)*4 + reg
#pragma unroll
  for (int mi = 0; mi < 4; ++mi) {
    const int row0 = tm + wm + mi * 16 + kg * 4;
#pragma unroll
    for (int nj = 0; nj < 4; ++nj) {
      const int col = tn + wn + nj * 16 + fr;
      const float bv = (col < Nlog) ? bias[col] : 0.f;
#pragma unroll
      for (int r = 0; r < 4; ++r) {
        float v = acc[mi][nj][r] + bv;
        if (ELU) v = (v > 0.f) ? v : expm1f(v);
        const int row = row0 + r;
        if (Cb) Cb[(size_t)row * N + col] = (bf16_t)v;
        if (Cf && col < Nlog) Cf[(size_t)row * Nlog + col] = v;
      }
    }
  }
}

// ---------------------------------------------------------------------------
// MFMA VQ: d = 0.5*||e||^2 - <z,e> via 16x16x32 bf16 MFMA (K padded with 0s).
// ---------------------------------------------------------------------------
__global__ __launch_bounds__(256) void vq_mfma(
    const float* __restrict__ ze, const float* __restrict__ emb,
    float* __restrict__ zq, bf16_t* __restrict__ zqb)
{
  __shared__ float  se[2048];
  __shared__ bf16_t seb[2048];
  const int t = threadIdx.x;
  for (int i = t; i < 2048; i += 256) { float v = emb[i]; se[i] = v; seb[i] = (bf16_t)v; }
  __syncthreads();

  const int l = t & 63, w = t >> 6;
  const int col = l & 15;
  const int ks8 = (l >> 4) * 8;
  const bool kact = (ks8 < 16);

  bf16x8 bfrag[8];
  float  hv[8];
#pragma unroll
  for (int cb = 0; cb < 8; ++cb) {
    float s = 0.f;
    bf16x8 bf;
#pragma unroll
    for (int j = 0; j < 8; ++j) bf[j] = (bf16_t)0.f;
    if (kact) {
      const float* ep = se + (cb * 16 + col) * 16 + ks8;
      float4 e0 = *(const float4*)ep;
      float4 e1 = *(const float4*)(ep + 4);
      bf[0] = (bf16_t)e0.x; bf[1] = (bf16_t)e0.y; bf[2] = (bf16_t)e0.z; bf[3] = (bf16_t)e0.w;
      bf[4] = (bf16_t)e1.x; bf[5] = (bf16_t)e1.y; bf[6] = (bf16_t)e1.z; bf[7] = (bf16_t)e1.w;
      s = e0.x*e0.x + e0.y*e0.y + e0.z*e0.z + e0.w*e0.w
        + e1.x*e1.x + e1.y*e1.y + e1.z*e1.z + e1.w*e1.w;
    }
    s += __shfl_xor(s, 16);
    s += __shfl_xor(s, 32);
    bfrag[cb] = bf;
    hv[cb] = 0.5f * s;
  }

  const int base_tile = blockIdx.x * 64 + w * 16;
  for (int it = 0; it < 16; ++it) {
    const int tile = base_tile + it;
    const int row = tile >> 3, g0 = (tile & 7) * 16;

    bf16x8 afrag;
#pragma unroll
    for (int j = 0; j < 8; ++j) afrag[j] = (bf16_t)0.f;
    if (kact) {
      const float* ap = ze + (size_t)row * 2048 + (g0 + col) * 16 + ks8;
      float4 a0 = *(const float4*)ap;
      float4 a1 = *(const float4*)(ap + 4);
      afrag[0] = (bf16_t)(-a0.x); afrag[1] = (bf16_t)(-a0.y);
      afrag[2] = (bf16_t)(-a0.z); afrag[3] = (bf16_t)(-a0.w);
      afrag[4] = (bf16_t)(-a1.x); afrag[5] = (bf16_t)(-a1.y);
      afrag[6] = (bf16_t)(-a1.z); afrag[7] = (bf16_t)(-a1.w);
    }

    f32x4 dd[8];
#pragma unroll
    for (int cb = 0; cb < 8; ++cb) {
      f32x4 c = (f32x4){hv[cb], hv[cb], hv[cb], hv[cb]};
      dd[cb] = __builtin_amdgcn_mfma_f32_16x16x32_bf16(afrag, bfrag[cb], c, 0, 0, 0);
    }

#pragma unroll
    for (int r = 0; r < 4; ++r) {
      float bd = dd[0][r]; int bi = col;
#pragma unroll
      for (int cb = 1; cb < 8; ++cb) {
        float v = dd[cb][r];
        int   ci = cb * 16 + col;
        if (v < bd) { bd = v; bi = ci; }
      }
#pragma unroll
      for (int m = 1; m < 16; m <<= 1) {
        float od = __shfl_xor(bd, m);
        int   oi = __shfl_xor(bi, m);
        if (od < bd || (od == bd && oi < bi)) { bd = od; bi = oi; }
      }
      if (col == r) {
        const int tok = (l >> 4) * 4 + r;
        const size_t go = ((size_t)row * 128 + g0 + tok) * 16;
        const float*  e  = se  + bi * 16;
        const bf16_t* eb = seb + bi * 16;
#pragma unroll
        for (int v = 0; v < 4; ++v)
          *(float4*)(zq + go + v * 4) = ((const float4*)e)[v];
        *(bf16x8*)(zqb + go)     = ((const bf16x8*)eb)[0];
        *(bf16x8*)(zqb + go + 8) = ((const bf16x8*)eb)[1];
      }
    }
  }
}

// ---------------------------------------------------------------------------
extern "C" void kernel_launch(void* const* d_in, const int* in_sizes, int n_in,
                              void* d_out, int out_size, void* d_ws, size_t ws_size,
                              hipStream_t stream)
{
  const float* y   = (const float*)d_in[0];
  const float* emb = (const float*)d_in[1];
  const float* eW1 = (const float*)d_in[2];
  const float* eb1 = (const float*)d_in[3];
  const float* eW2 = (const float*)d_in[4];
  const float* eb2 = (const float*)d_in[5];
  const float* eW3 = (const float*)d_in[6];
  const float* eb3 = (const float*)d_in[7];
  const float* dW1 = (const float*)d_in[8];
  const float* db1 = (const float*)d_in[9];
  const float* dW2 = (const float*)d_in[10];
  const float* db2 = (const float*)d_in[11];
  const float* dW3 = (const float*)d_in[12];
  const float* db3 = (const float*)d_in[13];

  float* out = (float*)d_out;               // [12800][2520]
  float* ze  = out + 32256000;              // [12800][2048]
  float* zq  = ze + 26214400;               // [12800][2048]

  uint8_t* ws = (uint8_t*)d_ws;
  size_t off = 0;
  auto alloc = [&](size_t bytes) -> void* {
    void* p = ws + off; off += (bytes + 255) & ~(size_t)255; return p;
  };
  bf16_t* X0  = (bf16_t*)alloc(12800ULL * 2560 * 2);
  bf16_t* W1t = (bf16_t*)alloc(1024ULL * 2560 * 2);
  bf16_t* W2t = (bf16_t*)alloc(1024ULL * 1024 * 2);
  bf16_t* W3t = (bf16_t*)alloc(2048ULL * 1024 * 2);
  bf16_t* V1t = (bf16_t*)alloc(1024ULL * 2048 * 2);
  bf16_t* V2t = (bf16_t*)alloc(1024ULL * 1024 * 2);
  bf16_t* V3t = (bf16_t*)alloc(2560ULL * 1024 * 2);
  bf16_t* H1  = (bf16_t*)alloc(12800ULL * 1024 * 2);
  bf16_t* H2  = (bf16_t*)alloc(12800ULL * 1024 * 2);
  bf16_t* ZQb = (bf16_t*)alloc(12800ULL * 2048 * 2);

  prep_kernel<<<27264, 256, 0, stream>>>(y, X0, eW1, W1t, eW2, W2t, eW3, W3t,
                                         dW1, V1t, dW2, V2t, dW3, V3t);

  // encoder
  gemm128<1><<<dim3(8, 50), 512, 0, stream>>>(X0, W1t, eb1, H1, nullptr, 12800, 1024, 2560, 1024);
  gemm128<1><<<dim3(8, 50), 512, 0, stream>>>(H1, W2t, eb2, H2, nullptr, 12800, 1024, 1024, 1024);
  gemm128<0><<<dim3(16, 50), 512, 0, stream>>>(H2, W3t, eb3, nullptr, ze, 12800, 2048, 1024, 2048);
  // vector quantize
  vq_mfma<<<1600, 256, 0, stream>>>(ze, emb, zq, ZQb);
  // decoder
  gemm128<1><<<dim3(8, 50), 512, 0, stream>>>(ZQb, V1t, db1, H1, nullptr, 12800, 1024, 2048, 1024);
  gemm128<1><<<dim3(8, 50), 512, 0, stream>>>(H1, V2t, db2, H2, nullptr, 12800, 1024, 1024, 1024);
  gemm128<0><<<dim3(20, 50), 512, 0, stream>>>(H2, V3t, db3, nullptr, out, 12800, 2560, 1024, 2520);
}

// Round 10
// 608.513 us; speedup vs baseline: 1.3821x; 1.0085x over previous
//
#include <hip/hip_runtime.h>
#include <hip/hip_bf16.h>
#include <cstdint>
#include <cstddef>

typedef __bf16 bf16_t;
typedef bf16_t bf16x8 __attribute__((ext_vector_type(8)));
typedef float  f32x4  __attribute__((ext_vector_type(4)));

__device__ __forceinline__ void gl_lds16(const void* g, void* l) {
  __builtin_amdgcn_global_load_lds(
      (const __attribute__((address_space(1))) void*)g,
      (__attribute__((address_space(3))) void*)l, 16, 0, 0);
}

#define BAR()  __builtin_amdgcn_s_barrier()

// ---------------------------------------------------------------------------
// prep kernel: fused pack_x0 + 6 weight transposes (fp32 -> bf16, KxN -> Npad x Kpad)
// ---------------------------------------------------------------------------
__device__ __forceinline__ void transpose_tile(
    const float* __restrict__ W, bf16_t* __restrict__ Wt,
    int K, int N, int Kpad, int Npad, int bx, int by, int t)
{
  __shared__ float tile[32][33];
  const int tx = t & 31, ty = t >> 5;
  const int k0 = bx * 32, n0 = by * 32;
#pragma unroll
  for (int i = 0; i < 4; ++i) {
    int k = k0 + ty + i * 8, n = n0 + tx;
    tile[ty + i * 8][tx] = (k < K && n < N) ? W[(size_t)k * N + n] : 0.f;
  }
  __syncthreads();
#pragma unroll
  for (int i = 0; i < 4; ++i) {
    int n = n0 + ty + i * 8, k = k0 + tx;
    if (n < Npad && k < Kpad)
      Wt[(size_t)n * Kpad + k] = (bf16_t)tile[tx][ty + i * 8];
  }
}

__global__ __launch_bounds__(256) void prep_kernel(
    const float* __restrict__ y, bf16_t* __restrict__ X0,
    const float* __restrict__ eW1, bf16_t* __restrict__ W1t,
    const float* __restrict__ eW2, bf16_t* __restrict__ W2t,
    const float* __restrict__ eW3, bf16_t* __restrict__ W3t,
    const float* __restrict__ dW1, bf16_t* __restrict__ V1t,
    const float* __restrict__ dW2, bf16_t* __restrict__ V2t,
    const float* __restrict__ dW3, bf16_t* __restrict__ V3t)
{
  const int b = blockIdx.x;
  const int t = threadIdx.x;
  if (b < 16000) {
    const int idx = b * 256 + t;
    const int r = idx / 320, c = (idx % 320) * 8;
    bf16x8 v;
    if (c < 2520) {
      const float4 f0 = *(const float4*)(y + (size_t)r * 2520 + c);
      const float4 f1 = *(const float4*)(y + (size_t)r * 2520 + c + 4);
      v[0] = (bf16_t)f0.x; v[1] = (bf16_t)f0.y; v[2] = (bf16_t)f0.z; v[3] = (bf16_t)f0.w;
      v[4] = (bf16_t)f1.x; v[5] = (bf16_t)f1.y; v[6] = (bf16_t)f1.z; v[7] = (bf16_t)f1.w;
    } else {
#pragma unroll
      for (int j = 0; j < 8; ++j) v[j] = (bf16_t)0.f;
    }
    *(bf16x8*)(X0 + (size_t)r * 2560 + c) = v;
    return;
  }
  int lb = b - 16000;
  if (lb < 2560)      { transpose_tile(eW1, W1t, 2520, 1024, 2560, 1024, lb % 80, lb / 80, t); return; }
  lb -= 2560;
  if (lb < 1024)      { transpose_tile(eW2, W2t, 1024, 1024, 1024, 1024, lb % 32, lb / 32, t); return; }
  lb -= 1024;
  if (lb < 2048)      { transpose_tile(eW3, W3t, 1024, 2048, 1024, 2048, lb % 32, lb / 32, t); return; }
  lb -= 2048;
  if (lb < 2048)      { transpose_tile(dW1, V1t, 2048, 1024, 2048, 1024, lb % 64, lb / 64, t); return; }
  lb -= 2048;
  if (lb < 1024)      { transpose_tile(dW2, V2t, 1024, 1024, 1024, 1024, lb % 32, lb / 32, t); return; }
  lb -= 1024;
  transpose_tile(dW3, V3t, 1024, 2520, 1024, 2560, lb % 32, lb / 32, t);
}

// ---------------------------------------------------------------------------
// 256x128 GEMM, BK=32, 3 LDS slots (72KB), depth-2 prefetch, counted vmcnt(3),
// single phase per K-tile, TWO blocks per CU (launch_bounds 512,4).
// R10: NO explicit lgkmcnt drain -- compiler emits fine-grained lgkmcnt so
// the first MFMAs overlap trailing ds_reads (m97/m141 evidence). Reads
// interleaved A/B so early MFMA operands land first.
// 8 waves (4M x 2N), wave tile 64x64.
// C[M][N] = A[M][K] @ Bt[N][K]^T + bias, optional ELU.
// Requires M%256==0, N%128==0, K%32==0, K/32 >= 2.
// ---------------------------------------------------------------------------
template<int ELU>
__global__ __launch_bounds__(512, 4) void gemm128(
    const bf16_t* __restrict__ A, const bf16_t* __restrict__ Bt,
    const float* __restrict__ bias,
    bf16_t* __restrict__ Cb, float* __restrict__ Cf,
    int M, int N, int K, int Nlog)
{
  // slot = A 256x32 (8192 el) + B 128x32 (4096 el) = 12288 el = 24KB; 3 slots
  __shared__ __align__(16) bf16_t lds[36864];

  const int t  = threadIdx.x;
  const int w  = t >> 6, l = t & 63;
  const int fr = l & 15, kg = l >> 4;
  const int wm = (w >> 1) * 64, wn = (w & 1) * 64;   // 4M x 2N waves

  // bijective XCD-aware remap (m204)
  const int gx = gridDim.x;
  const int nwg = gx * (int)gridDim.y;
  int lin = blockIdx.y * gx + blockIdx.x;
  int q8 = nwg >> 3, r8 = nwg & 7, xcd = lin & 7, idx = lin >> 3;
  int swz = (xcd < r8 ? xcd * (q8 + 1) : r8 * (q8 + 1) + (xcd - r8) * q8) + idx;
  const int tn = (swz % gx) * 128;
  const int tm = (swz / gx) * 256;

  const int srow = t >> 2;
  const int scol = (t & 3) * 8;
  const int sdst = t * 8;

  const int NT = K >> 5;

  f32x4 acc[4][4];
#pragma unroll
  for (int i = 0; i < 4; ++i)
#pragma unroll
    for (int j = 0; j < 4; ++j) acc[i][j] = (f32x4){0.f, 0.f, 0.f, 0.f};

  auto stage = [&](int slot, int kn) {
    bf16_t* d = lds + slot * 12288;
    gl_lds16(A  + (size_t)(tm + srow) * K + kn + scol,       d + sdst);
    gl_lds16(A  + (size_t)(tm + 128 + srow) * K + kn + scol, d + 4096 + sdst);
    gl_lds16(Bt + (size_t)(tn + srow) * K + kn + scol,       d + 8192 + sdst);
  };

  // prologue: stage tiles 0,1; wait for tile 0 (leave tile 1's 3 in flight).
  stage(0, 0);
  stage(1, 32);
  asm volatile("s_waitcnt vmcnt(3)" ::: "memory");
  BAR();

  for (int kt = 0; kt < NT; ++kt) {
    const int slot = kt % 3;
    const bf16_t* aH = lds + slot * 12288 + wm * 32;          // wave's 64-row A view
    const bf16_t* bH = lds + slot * 12288 + 8192 + wn * 32;   // wave's 64-row B view

    // stage tile kt+2 (slot (kt+2)%3: last read at tile kt-1, drained)
    if (kt + 2 < NT) stage((kt + 2) % 3, (kt + 2) << 5);

    // interleaved reads: first MFMA's operands (af[0], bf_[0]) issue first;
    // NO explicit lgkmcnt -- compiler inserts fine-grained waits per use.
    bf16x8 af[4], bf_[4];
#pragma unroll
    for (int q = 0; q < 4; ++q) {
      af[q]  = *(const bf16x8*)(aH + (q * 16 + fr) * 32 + kg * 8);
      bf_[q] = *(const bf16x8*)(bH + (q * 16 + fr) * 32 + kg * 8);
    }
    __builtin_amdgcn_s_setprio(1);
#pragma unroll
    for (int mi = 0; mi < 4; ++mi)
#pragma unroll
      for (int nj = 0; nj < 4; ++nj)
        acc[mi][nj] = __builtin_amdgcn_mfma_f32_16x16x32_bf16(af[mi], bf_[nj], acc[mi][nj], 0, 0, 0);
    __builtin_amdgcn_s_setprio(0);
    // leave tile kt+2's 3 loads in flight -> tile kt+1 resident
    asm volatile("s_waitcnt vmcnt(3)" ::: "memory");
    BAR();
  }

  // epilogue: C/D layout col = lane&15, row = (lane>>4)*4 + reg
#pragma unroll
  for (int mi = 0; mi < 4; ++mi) {
    const int row0 = tm + wm + mi * 16 + kg * 4;
#pragma unroll
    for (int nj = 0; nj < 4; ++nj) {
      const int col = tn + wn + nj * 16 + fr;
      const float bv = (col < Nlog) ? bias[col] : 0.f;
#pragma unroll
      for (int r = 0; r < 4; ++r) {
        float v = acc[mi][nj][r] + bv;
        if (ELU) v = (v > 0.f) ? v : expm1f(v);
        const int row = row0 + r;
        if (Cb) Cb[(size_t)row * N + col] = (bf16_t)v;
        if (Cf && col < Nlog) Cf[(size_t)row * Nlog + col] = v;
      }
    }
  }
}

// ---------------------------------------------------------------------------
// MFMA VQ: d = 0.5*||e||^2 - <z,e> via 16x16x32 bf16 MFMA (K padded with 0s).
// ---------------------------------------------------------------------------
__global__ __launch_bounds__(256) void vq_mfma(
    const float* __restrict__ ze, const float* __restrict__ emb,
    float* __restrict__ zq, bf16_t* __restrict__ zqb)
{
  __shared__ float  se[2048];
  __shared__ bf16_t seb[2048];
  const int t = threadIdx.x;
  for (int i = t; i < 2048; i += 256) { float v = emb[i]; se[i] = v; seb[i] = (bf16_t)v; }
  __syncthreads();

  const int l = t & 63, w = t >> 6;
  const int col = l & 15;
  const int ks8 = (l >> 4) * 8;
  const bool kact = (ks8 < 16);

  bf16x8 bfrag[8];
  float  hv[8];
#pragma unroll
  for (int cb = 0; cb < 8; ++cb) {
    float s = 0.f;
    bf16x8 bf;
#pragma unroll
    for (int j = 0; j < 8; ++j) bf[j] = (bf16_t)0.f;
    if (kact) {
      const float* ep = se + (cb * 16 + col) * 16 + ks8;
      float4 e0 = *(const float4*)ep;
      float4 e1 = *(const float4*)(ep + 4);
      bf[0] = (bf16_t)e0.x; bf[1] = (bf16_t)e0.y; bf[2] = (bf16_t)e0.z; bf[3] = (bf16_t)e0.w;
      bf[4] = (bf16_t)e1.x; bf[5] = (bf16_t)e1.y; bf[6] = (bf16_t)e1.z; bf[7] = (bf16_t)e1.w;
      s = e0.x*e0.x + e0.y*e0.y + e0.z*e0.z + e0.w*e0.w
        + e1.x*e1.x + e1.y*e1.y + e1.z*e1.z + e1.w*e1.w;
    }
    s += __shfl_xor(s, 16);
    s += __shfl_xor(s, 32);
    bfrag[cb] = bf;
    hv[cb] = 0.5f * s;
  }

  const int base_tile = blockIdx.x * 64 + w * 16;
  for (int it = 0; it < 16; ++it) {
    const int tile = base_tile + it;
    const int row = tile >> 3, g0 = (tile & 7) * 16;

    bf16x8 afrag;
#pragma unroll
    for (int j = 0; j < 8; ++j) afrag[j] = (bf16_t)0.f;
    if (kact) {
      const float* ap = ze + (size_t)row * 2048 + (g0 + col) * 16 + ks8;
      float4 a0 = *(const float4*)ap;
      float4 a1 = *(const float4*)(ap + 4);
      afrag[0] = (bf16_t)(-a0.x); afrag[1] = (bf16_t)(-a0.y);
      afrag[2] = (bf16_t)(-a0.z); afrag[3] = (bf16_t)(-a0.w);
      afrag[4] = (bf16_t)(-a1.x); afrag[5] = (bf16_t)(-a1.y);
      afrag[6] = (bf16_t)(-a1.z); afrag[7] = (bf16_t)(-a1.w);
    }

    f32x4 dd[8];
#pragma unroll
    for (int cb = 0; cb < 8; ++cb) {
      f32x4 c = (f32x4){hv[cb], hv[cb], hv[cb], hv[cb]};
      dd[cb] = __builtin_amdgcn_mfma_f32_16x16x32_bf16(afrag, bfrag[cb], c, 0, 0, 0);
    }

#pragma unroll
    for (int r = 0; r < 4; ++r) {
      float bd = dd[0][r]; int bi = col;
#pragma unroll
      for (int cb = 1; cb < 8; ++cb) {
        float v = dd[cb][r];
        int   ci = cb * 16 + col;
        if (v < bd) { bd = v; bi = ci; }
      }
#pragma unroll
      for (int m = 1; m < 16; m <<= 1) {
        float od = __shfl_xor(bd, m);
        int   oi = __shfl_xor(bi, m);
        if (od < bd || (od == bd && oi < bi)) { bd = od; bi = oi; }
      }
      if (col == r) {
        const int tok = (l >> 4) * 4 + r;
        const size_t go = ((size_t)row * 128 + g0 + tok) * 16;
        const float*  e  = se  + bi * 16;
        const bf16_t* eb = seb + bi * 16;
#pragma unroll
        for (int v = 0; v < 4; ++v)
          *(float4*)(zq + go + v * 4) = ((const float4*)e)[v];
        *(bf16x8*)(zqb + go)     = ((const bf16x8*)eb)[0];
        *(bf16x8*)(zqb + go + 8) = ((const bf16x8*)eb)[1];
      }
    }
  }
}

// ---------------------------------------------------------------------------
extern "C" void kernel_launch(void* const* d_in, const int* in_sizes, int n_in,
                              void* d_out, int out_size, void* d_ws, size_t ws_size,
                              hipStream_t stream)
{
  const float* y   = (const float*)d_in[0];
  const float* emb = (const float*)d_in[1];
  const float* eW1 = (const float*)d_in[2];
  const float* eb1 = (const float*)d_in[3];
  const float* eW2 = (const float*)d_in[4];
  const float* eb2 = (const float*)d_in[5];
  const float* eW3 = (const float*)d_in[6];
  const float* eb3 = (const float*)d_in[7];
  const float* dW1 = (const float*)d_in[8];
  const float* db1 = (const float*)d_in[9];
  const float* dW2 = (const float*)d_in[10];
  const float* db2 = (const float*)d_in[11];
  const float* dW3 = (const float*)d_in[12];
  const float* db3 = (const float*)d_in[13];

  float* out = (float*)d_out;               // [12800][2520]
  float* ze  = out + 32256000;              // [12800][2048]
  float* zq  = ze + 26214400;               // [12800][2048]

  uint8_t* ws = (uint8_t*)d_ws;
  size_t off = 0;
  auto alloc = [&](size_t bytes) -> void* {
    void* p = ws + off; off += (bytes + 255) & ~(size_t)255; return p;
  };
  bf16_t* X0  = (bf16_t*)alloc(12800ULL * 2560 * 2);
  bf16_t* W1t = (bf16_t*)alloc(1024ULL * 2560 * 2);
  bf16_t* W2t = (bf16_t*)alloc(1024ULL * 1024 * 2);
  bf16_t* W3t = (bf16_t*)alloc(2048ULL * 1024 * 2);
  bf16_t* V1t = (bf16_t*)alloc(1024ULL * 2048 * 2);
  bf16_t* V2t = (bf16_t*)alloc(1024ULL * 1024 * 2);
  bf16_t* V3t = (bf16_t*)alloc(2560ULL * 1024 * 2);
  bf16_t* H1  = (bf16_t*)alloc(12800ULL * 1024 * 2);
  bf16_t* H2  = (bf16_t*)alloc(12800ULL * 1024 * 2);
  bf16_t* ZQb = (bf16_t*)alloc(12800ULL * 2048 * 2);

  prep_kernel<<<27264, 256, 0, stream>>>(y, X0, eW1, W1t, eW2, W2t, eW3, W3t,
                                         dW1, V1t, dW2, V2t, dW3, V3t);

  // encoder
  gemm128<1><<<dim3(8, 50), 512, 0, stream>>>(X0, W1t, eb1, H1, nullptr, 12800, 1024, 2560, 1024);
  gemm128<1><<<dim3(8, 50), 512, 0, stream>>>(H1, W2t, eb2, H2, nullptr, 12800, 1024, 1024, 1024);
  gemm128<0><<<dim3(16, 50), 512, 0, stream>>>(H2, W3t, eb3, nullptr, ze, 12800, 2048, 1024, 2048);
  // vector quantize
  vq_mfma<<<1600, 256, 0, stream>>>(ze, emb, zq, ZQb);
  // decoder
  gemm128<1><<<dim3(8, 50), 512, 0, stream>>>(ZQb, V1t, db1, H1, nullptr, 12800, 1024, 2048, 1024);
  gemm128<1><<<dim3(8, 50), 512, 0, stream>>>(H1, V2t, db2, H2, nullptr, 12800, 1024, 1024, 1024);
  gemm128<0><<<dim3(20, 50), 512, 0, stream>>>(H2, V3t, db3, nullptr, out, 12800, 2560, 1024, 2520);
}